// Round 1
// baseline (1408.174 us; speedup 1.0000x reference)
//
#include <hip/hip_runtime.h>
#include <math.h>

// Problem constants
constexpr int B_ = 2, S_ = 1024, DM_ = 1024, NH_ = 16, HD_ = 64;

// ---------------------------------------------------------------------------
// Tiled fp32 GEMM: C = scale * (A @ W^T) [+ bias], batched over z=(b*NH+h).
// A: (M x K) row-major, lda. W: (N x K) row-major, ldw (i.e. NT GEMM, both
// operands K-contiguous). mode 0: plain write. mode 1: hedgehog feature-map
// epilogue — writes exp(v) at col n and exp(-v) at col n+64 (N must be 64).
// All M,N divisible by BM,BN; K divisible by BK (true for every launch here).
// ---------------------------------------------------------------------------
template <int BM, int BN, int TM, int TN, int BK>
__global__ __launch_bounds__(256) void gemm_nt(
    const float* __restrict__ A, const float* __restrict__ W,
    const float* __restrict__ bias, float* __restrict__ C,
    int M, int N, int K, int lda, int ldw, int ldc,
    long sAb, long sAh, long sWb, long sWh, long sCz,
    float scale, int mode)
{
    const int z = blockIdx.z;
    const int b = z / NH_, h = z % NH_;
    const float* Ab = A + (long)b * sAb + (long)h * sAh;
    const float* Wb = W + (long)b * sWb + (long)h * sWh;
    float* Cb = C + (long)z * sCz;

    __shared__ float As[BK][BM + 4];
    __shared__ float Ws[BK][BN + 4];

    const int t = threadIdx.x;          // 256 threads
    constexpr int TX = BN / TN;         // threads along n
    const int tx = t % TX, ty = t / TX;
    const int m0 = blockIdx.y * BM, n0 = blockIdx.x * BN;

    float acc[TM][TN];
#pragma unroll
    for (int i = 0; i < TM; ++i)
#pragma unroll
        for (int j = 0; j < TN; ++j) acc[i][j] = 0.f;

    for (int k0 = 0; k0 < K; k0 += BK) {
#pragma unroll
        for (int i = 0; i < (BM * BK) / 256; ++i) {
            int idx = t + i * 256;
            int r = idx / BK, c = idx % BK;
            As[c][r] = Ab[(long)(m0 + r) * lda + k0 + c];
        }
#pragma unroll
        for (int i = 0; i < (BN * BK) / 256; ++i) {
            int idx = t + i * 256;
            int r = idx / BK, c = idx % BK;
            Ws[c][r] = Wb[(long)(n0 + r) * ldw + k0 + c];
        }
        __syncthreads();
#pragma unroll
        for (int kk = 0; kk < BK; ++kk) {
            float a[TM], w[TN];
#pragma unroll
            for (int i = 0; i < TM; ++i) a[i] = As[kk][ty * TM + i];
#pragma unroll
            for (int j = 0; j < TN; ++j) w[j] = Ws[kk][tx * TN + j];
#pragma unroll
            for (int i = 0; i < TM; ++i)
#pragma unroll
                for (int j = 0; j < TN; ++j)
                    acc[i][j] = fmaf(a[i], w[j], acc[i][j]);
        }
        __syncthreads();
    }

#pragma unroll
    for (int i = 0; i < TM; ++i) {
        int m = m0 + ty * TM + i;
#pragma unroll
        for (int j = 0; j < TN; ++j) {
            int n = n0 + tx * TN + j;
            float v = acc[i][j] * scale;
            if (bias) v += bias[n];
            if (mode == 0) {
                Cb[(long)m * ldc + n] = v;
            } else {
                // hedgehog feature map: concat(exp(y), exp(-y))
                Cb[(long)m * ldc + n] = expf(v);
                Cb[(long)m * ldc + 64 + n] = expf(-v);
            }
        }
    }
}

// ---------------------------------------------------------------------------
// Tiled fp32 NN GEMM (for ctx = P @ V): C = A @ B, A (M x K) lda, B (K x N) ldb.
// A batched by z stride; B and C batched by (b,h) strides.
// ---------------------------------------------------------------------------
template <int BM, int BN, int TM, int TN, int BK>
__global__ __launch_bounds__(256) void gemm_nn(
    const float* __restrict__ A, const float* __restrict__ Bm,
    float* __restrict__ C, int M, int N, int K, int lda, int ldb, int ldc,
    long sAz, long sBb, long sBh, long sCb, long sCh)
{
    const int z = blockIdx.z;
    const int b = z / NH_, h = z % NH_;
    const float* Ab = A + (long)z * sAz;
    const float* Bb = Bm + (long)b * sBb + (long)h * sBh;
    float* Cb = C + (long)b * sCb + (long)h * sCh;

    __shared__ float As[BK][BM + 4];
    __shared__ float Bs[BK][BN + 4];

    const int t = threadIdx.x;
    constexpr int TX = BN / TN;
    const int tx = t % TX, ty = t / TX;
    const int m0 = blockIdx.y * BM, n0 = blockIdx.x * BN;

    float acc[TM][TN];
#pragma unroll
    for (int i = 0; i < TM; ++i)
#pragma unroll
        for (int j = 0; j < TN; ++j) acc[i][j] = 0.f;

    for (int k0 = 0; k0 < K; k0 += BK) {
#pragma unroll
        for (int i = 0; i < (BM * BK) / 256; ++i) {
            int idx = t + i * 256;
            int r = idx / BK, c = idx % BK;
            As[c][r] = Ab[(long)(m0 + r) * lda + k0 + c];
        }
#pragma unroll
        for (int i = 0; i < (BN * BK) / 256; ++i) {
            int idx = t + i * 256;
            int r = idx / BN, c = idx % BN;   // row = k, col = n (B is n-contiguous)
            Bs[r][c] = Bb[(long)(k0 + r) * ldb + n0 + c];
        }
        __syncthreads();
#pragma unroll
        for (int kk = 0; kk < BK; ++kk) {
            float a[TM], w[TN];
#pragma unroll
            for (int i = 0; i < TM; ++i) a[i] = As[kk][ty * TM + i];
#pragma unroll
            for (int j = 0; j < TN; ++j) w[j] = Bs[kk][tx * TN + j];
#pragma unroll
            for (int i = 0; i < TM; ++i)
#pragma unroll
                for (int j = 0; j < TN; ++j)
                    acc[i][j] = fmaf(a[i], w[j], acc[i][j]);
        }
        __syncthreads();
    }

#pragma unroll
    for (int i = 0; i < TM; ++i) {
        int m = m0 + ty * TM + i;
#pragma unroll
        for (int j = 0; j < TN; ++j) {
            int n = n0 + tx * TN + j;
            Cb[(long)m * ldc + n] = acc[i][j];
        }
    }
}

// ---------------------------------------------------------------------------
// In-place softmax over rows of length 1024. One block (256 thr) per row.
// ---------------------------------------------------------------------------
__global__ __launch_bounds__(256) void softmax_rows(float* __restrict__ data)
{
    const long row = blockIdx.x;
    float* p = data + row * (long)S_;
    const int t = threadIdx.x;
    float x[4];
#pragma unroll
    for (int i = 0; i < 4; ++i) x[i] = p[t + i * 256];

    float m = fmaxf(fmaxf(x[0], x[1]), fmaxf(x[2], x[3]));
#pragma unroll
    for (int o = 32; o > 0; o >>= 1) m = fmaxf(m, __shfl_down(m, o, 64));
    __shared__ float sm[4];
    if ((t & 63) == 0) sm[t >> 6] = m;
    __syncthreads();
    m = fmaxf(fmaxf(sm[0], sm[1]), fmaxf(sm[2], sm[3]));

    float s = 0.f;
#pragma unroll
    for (int i = 0; i < 4; ++i) { x[i] = expf(x[i] - m); s += x[i]; }
#pragma unroll
    for (int o = 32; o > 0; o >>= 1) s += __shfl_down(s, o, 64);
    __shared__ float ss[4];
    if ((t & 63) == 0) ss[t >> 6] = s;
    __syncthreads();
    s = ss[0] + ss[1] + ss[2] + ss[3];

    float inv = 1.f / s;
#pragma unroll
    for (int i = 0; i < 4; ++i) p[t + i * 256] = x[i] * inv;
}

// ---------------------------------------------------------------------------
// In-place sum-normalize over rows of length 1024 (pred_attns).
// ---------------------------------------------------------------------------
__global__ __launch_bounds__(256) void norm_rows(float* __restrict__ data)
{
    const long row = blockIdx.x;
    float* p = data + row * (long)S_;
    const int t = threadIdx.x;
    float x[4];
#pragma unroll
    for (int i = 0; i < 4; ++i) x[i] = p[t + i * 256];

    float s = x[0] + x[1] + x[2] + x[3];
#pragma unroll
    for (int o = 32; o > 0; o >>= 1) s += __shfl_down(s, o, 64);
    __shared__ float ss[4];
    if ((t & 63) == 0) ss[t >> 6] = s;
    __syncthreads();
    s = ss[0] + ss[1] + ss[2] + ss[3];

    float inv = 1.f / s;
#pragma unroll
    for (int i = 0; i < 4; ++i) p[t + i * 256] = x[i] * inv;
}

// ---------------------------------------------------------------------------
extern "C" void kernel_launch(void* const* d_in, const int* in_sizes, int n_in,
                              void* d_out, int out_size, void* d_ws, size_t ws_size,
                              hipStream_t stream)
{
    (void)in_sizes; (void)n_in; (void)out_size; (void)ws_size;

    const float* hs  = (const float*)d_in[0];
    const float* Wq  = (const float*)d_in[1];
    const float* bq  = (const float*)d_in[2];
    const float* Wk  = (const float*)d_in[3];
    const float* bk  = (const float*)d_in[4];
    const float* Wv  = (const float*)d_in[5];
    const float* bv  = (const float*)d_in[6];
    const float* Wo  = (const float*)d_in[7];
    const float* bo  = (const float*)d_in[8];
    const float* Wfq = (const float*)d_in[9];
    const float* bfq = (const float*)d_in[10];
    const float* Wfk = (const float*)d_in[11];
    const float* bfk = (const float*)d_in[12];

    float* out0  = (float*)d_out;                       // (B,S,DM)
    float* pred  = out0 + (long)B_ * S_ * DM_;          // (B,H,S,S)
    float* trueA = pred + (long)B_ * NH_ * S_ * S_;     // (B,H,S,S)

    float* ws  = (float*)d_ws;
    float* Q   = ws;                 // 2048x1024
    float* Km  = Q   + 2097152;      // 2048x1024
    float* V   = Km  + 2097152;      // 2048x1024
    float* ctx = V   + 2097152;      // 2048x1024 (already in (B,S,H*D) layout)
    float* fq  = ctx + 2097152;      // (B,H,S,128)
    float* fk  = fq  + 4194304;      // (B,H,S,128)

    const dim3 blk(256);
    const long SD = (long)S_ * DM_;
    const long SS = (long)S_ * S_;

    // 1) QKV projections: X (2048x1024) @ W^T + b
    dim3 gproj(DM_ / 128, (B_ * S_) / 128, 1);
    gemm_nt<128,128,8,8,16><<<gproj, blk, 0, stream>>>(
        hs, Wq, bq, Q, B_ * S_, DM_, DM_, DM_, DM_, DM_, 0, 0, 0, 0, 0, 1.f, 0);
    gemm_nt<128,128,8,8,16><<<gproj, blk, 0, stream>>>(
        hs, Wk, bk, Km, B_ * S_, DM_, DM_, DM_, DM_, DM_, 0, 0, 0, 0, 0, 1.f, 0);
    gemm_nt<128,128,8,8,16><<<gproj, blk, 0, stream>>>(
        hs, Wv, bv, V, B_ * S_, DM_, DM_, DM_, DM_, DM_, 0, 0, 0, 0, 0, 1.f, 0);

    // 2) raw scores -> true_attns region: per (b,h), Qh @ Kh^T / 8
    dim3 gsc(S_ / 128, S_ / 128, B_ * NH_);
    gemm_nt<128,128,8,8,16><<<gsc, blk, 0, stream>>>(
        Q, Km, nullptr, trueA, S_, S_, HD_, DM_, DM_, S_,
        SD, HD_, SD, HD_, SS, 0.125f, 0);

    // 3) softmax in place
    softmax_rows<<<B_ * NH_ * S_, blk, 0, stream>>>(trueA);

    // 4) ctx = P @ V  (written directly in (B,S,H*D) layout)
    dim3 gctx(1, S_ / 64, B_ * NH_);
    gemm_nn<64,64,4,4,16><<<gctx, blk, 0, stream>>>(
        trueA, V, ctx, S_, HD_, S_, S_, DM_, DM_,
        SS, SD, HD_, SD, HD_);

    // 5) outputs = ctx @ Wo^T + bo
    gemm_nt<128,128,8,8,16><<<gproj, blk, 0, stream>>>(
        ctx, Wo, bo, out0, B_ * S_, DM_, DM_, DM_, DM_, DM_, 0, 0, 0, 0, 0, 1.f, 0);

    // 6) feature maps: fq = [exp(Qh@Wfq^T+bfq), exp(-(...))], (B,H,S,128)
    dim3 gfm(1, S_ / 64, B_ * NH_);
    gemm_nt<64,64,4,4,16><<<gfm, blk, 0, stream>>>(
        Q, Wfq, bfq, fq, S_, HD_, HD_, DM_, HD_, 128,
        SD, HD_, 0, 0, (long)S_ * 128, 1.f, 1);
    gemm_nt<64,64,4,4,16><<<gfm, blk, 0, stream>>>(
        Km, Wfk, bfk, fk, S_, HD_, HD_, DM_, HD_, 128,
        SD, HD_, 0, 0, (long)S_ * 128, 1.f, 1);

    // 7) raw qk -> pred_attns region: per (b,h), fq @ fk^T  (K=128)
    dim3 gqk(S_ / 128, S_ / 128, B_ * NH_);
    gemm_nt<128,128,8,8,16><<<gqk, blk, 0, stream>>>(
        fq, fk, nullptr, pred, S_, S_, 128, 128, 128, S_,
        (long)NH_ * S_ * 128, (long)S_ * 128, (long)NH_ * S_ * 128, (long)S_ * 128,
        SS, 1.f, 0);

    // 8) sum-normalize rows in place
    norm_rows<<<B_ * NH_ * S_, blk, 0, stream>>>(pred);
}

// Round 2
// 538.938 us; speedup vs baseline: 2.6129x; 2.6129x over previous
//
#include <hip/hip_runtime.h>
#include <math.h>

constexpr int B_ = 2, S_ = 1024, DM_ = 1024, NH_ = 16, HD_ = 64;
constexpr long SD = (long)S_ * DM_;   // per-batch hidden stride (1M)
constexpr long SS = (long)S_ * S_;    // per-head attn stride (1M)

typedef _Float16 half8 __attribute__((ext_vector_type(8)));
typedef _Float16 half4 __attribute__((ext_vector_type(4)));
typedef float floatx4 __attribute__((ext_vector_type(4)));

// async global->LDS, 16 B per lane; LDS dst is wave-uniform base + lane*16
__device__ __forceinline__ void gl_lds16(const void* g, void* l) {
    __builtin_amdgcn_global_load_lds(
        (const __attribute__((address_space(1))) void*)g,
        (__attribute__((address_space(3))) void*)l, 16, 0, 0);
}

// ---------------------------------------------------------------------------
// fp32 -> fp16 convert (4 elems/thread)
// ---------------------------------------------------------------------------
__global__ __launch_bounds__(256) void cvt_f2h(
    const float* __restrict__ x, _Float16* __restrict__ y, int n4)
{
    int i = (blockIdx.x * 256 + threadIdx.x);
    if (i < n4) {
        float4 v = ((const float4*)x)[i];
        half4 h = { (_Float16)v.x, (_Float16)v.y, (_Float16)v.z, (_Float16)v.w };
        ((half4*)y)[i] = h;
    }
}

// ---------------------------------------------------------------------------
// Unified NT MFMA GEMM: C = scale*(A @ W^T) [+bias].
// A: (M x K) k-contiguous (fp16, or fp32 when CONVA=1 -> converted in staging).
// W: (N x K) k-contiguous fp16. Batched over z=(b*NH+h) via element strides.
// mode 0: fp32 out (Cf).  mode 1: fp16 out (Ch).
// Block 256 = 4 waves in 2x2; wave computes WM x WN via 16x16x32 f16 MFMA.
// BK = 32 (one MFMA K-depth).
// ---------------------------------------------------------------------------
template <int BM, int BN, int WM, int WN, int CONVA>
__global__ __launch_bounds__(256) void mm_nt(
    const void* __restrict__ Ap, const _Float16* __restrict__ Wp,
    const float* __restrict__ bias, float* __restrict__ Cf,
    _Float16* __restrict__ Ch, int K, int lda, int ldw, int ldc,
    long sAb, long sAh, long sWb, long sWh, long sCb, long sCh,
    float scale, int mode)
{
    constexpr int MI = WM / 16, NI = WN / 16;
    const int z = blockIdx.z, b = z / NH_, h = z % NH_;
    const int wave = threadIdx.x >> 6, lane = threadIdx.x & 63;
    const int m0 = blockIdx.y * BM, n0 = blockIdx.x * BN;
    const int wm = (wave >> 1) * WM, wn = (wave & 1) * WN;
    const int r16 = lane & 15, quad = lane >> 4;

    const _Float16* Wz = Wp + (long)b * sWb + (long)h * sWh;

    __shared__ __align__(16) _Float16 As[BM * 32];
    __shared__ __align__(16) _Float16 Bs[BN * 32];

    floatx4 acc[MI][NI];
#pragma unroll
    for (int i = 0; i < MI; ++i)
#pragma unroll
        for (int j = 0; j < NI; ++j)
#pragma unroll
            for (int r = 0; r < 4; ++r) acc[i][j][r] = 0.f;

    for (int k0 = 0; k0 < K; k0 += 32) {
        if constexpr (CONVA) {
            // A is fp32: load via VGPR, convert, ds_write
            const float* Af = (const float*)Ap + (long)b * sAb + (long)h * sAh;
#pragma unroll
            for (int r = 0; r < BM / 32; ++r) {
                int idx = r * 1024 + threadIdx.x * 4;
                int row = idx >> 5, col = idx & 31;
                float4 v = *(const float4*)(Af + (long)(m0 + row) * lda + k0 + col);
                half4 hv = { (_Float16)v.x, (_Float16)v.y, (_Float16)v.z, (_Float16)v.w };
                *(half4*)&As[row * 32 + col] = hv;
            }
        } else {
            const _Float16* Ah = (const _Float16*)Ap + (long)b * sAb + (long)h * sAh;
#pragma unroll
            for (int c = wave * (BM / 64); c < (wave + 1) * (BM / 64); ++c) {
                const _Float16* g = Ah + (long)(m0 + c * 16 + (lane >> 2)) * lda
                                    + k0 + (lane & 3) * 8;
                gl_lds16(g, &As[c * 512]);
            }
        }
#pragma unroll
        for (int c = wave * (BN / 64); c < (wave + 1) * (BN / 64); ++c) {
            const _Float16* g = Wz + (long)(n0 + c * 16 + (lane >> 2)) * ldw
                                + k0 + (lane & 3) * 8;
            gl_lds16(g, &Bs[c * 512]);
        }
        __syncthreads();

        half8 af[MI], bf8[NI];
#pragma unroll
        for (int i = 0; i < MI; ++i)
            af[i] = *(const half8*)&As[(wm + i * 16 + r16) * 32 + quad * 8];
#pragma unroll
        for (int j = 0; j < NI; ++j)
            bf8[j] = *(const half8*)&Bs[(wn + j * 16 + r16) * 32 + quad * 8];
#pragma unroll
        for (int i = 0; i < MI; ++i)
#pragma unroll
            for (int j = 0; j < NI; ++j)
                acc[i][j] = __builtin_amdgcn_mfma_f32_16x16x32_f16(
                    af[i], bf8[j], acc[i][j], 0, 0, 0);
        __syncthreads();
    }

    const long cb = (long)b * sCb + (long)h * sCh;
#pragma unroll
    for (int i = 0; i < MI; ++i) {
#pragma unroll
        for (int j = 0; j < NI; ++j) {
#pragma unroll
            for (int r = 0; r < 4; ++r) {
                int row = m0 + wm + i * 16 + quad * 4 + r;
                int col = n0 + wn + j * 16 + r16;
                float v = acc[i][j][r] * scale;
                if (bias) v += bias[col];
                if (mode == 0) Cf[cb + (long)row * ldc + col] = v;
                else           Ch[cb + (long)row * ldc + col] = (_Float16)v;
            }
        }
    }
}

// ---------------------------------------------------------------------------
// Fused QKV projection: z = blockIdx.z selects {Q,K,V}. M=2048, N=1024, K=1024.
// Q,K written fp16 row-major; V written fp16 TRANSPOSED per head:
// VtH[((b*16+h)*64+d)*1024 + s].
// ---------------------------------------------------------------------------
__global__ __launch_bounds__(256) void qkv_proj(
    const _Float16* __restrict__ hsH,
    const _Float16* __restrict__ W0, const _Float16* __restrict__ W1,
    const _Float16* __restrict__ W2,
    const float* __restrict__ b0, const float* __restrict__ b1,
    const float* __restrict__ b2,
    _Float16* __restrict__ QH, _Float16* __restrict__ KH,
    _Float16* __restrict__ VtH)
{
    const int z = blockIdx.z;
    const _Float16* W = (z == 0) ? W0 : (z == 1) ? W1 : W2;
    const float* bias = (z == 0) ? b0 : (z == 1) ? b1 : b2;

    const int wave = threadIdx.x >> 6, lane = threadIdx.x & 63;
    const int m0 = blockIdx.y * 128, n0 = blockIdx.x * 128;
    const int wm = (wave >> 1) * 64, wn = (wave & 1) * 64;
    const int r16 = lane & 15, quad = lane >> 4;

    __shared__ __align__(16) _Float16 As[128 * 32];
    __shared__ __align__(16) _Float16 Bs[128 * 32];

    floatx4 acc[4][4];
#pragma unroll
    for (int i = 0; i < 4; ++i)
#pragma unroll
        for (int j = 0; j < 4; ++j)
#pragma unroll
            for (int r = 0; r < 4; ++r) acc[i][j][r] = 0.f;

    for (int k0 = 0; k0 < 1024; k0 += 32) {
#pragma unroll
        for (int c = wave * 2; c < wave * 2 + 2; ++c) {
            const _Float16* ga = hsH + (long)(m0 + c * 16 + (lane >> 2)) * 1024
                                 + k0 + (lane & 3) * 8;
            gl_lds16(ga, &As[c * 512]);
            const _Float16* gb = W + (long)(n0 + c * 16 + (lane >> 2)) * 1024
                                 + k0 + (lane & 3) * 8;
            gl_lds16(gb, &Bs[c * 512]);
        }
        __syncthreads();

        half8 af[4], bf8[4];
#pragma unroll
        for (int i = 0; i < 4; ++i)
            af[i] = *(const half8*)&As[(wm + i * 16 + r16) * 32 + quad * 8];
#pragma unroll
        for (int j = 0; j < 4; ++j)
            bf8[j] = *(const half8*)&Bs[(wn + j * 16 + r16) * 32 + quad * 8];
#pragma unroll
        for (int i = 0; i < 4; ++i)
#pragma unroll
            for (int j = 0; j < 4; ++j)
                acc[i][j] = __builtin_amdgcn_mfma_f32_16x16x32_f16(
                    af[i], bf8[j], acc[i][j], 0, 0, 0);
        __syncthreads();
    }

    _Float16* dst = (z == 0) ? QH : KH;
#pragma unroll
    for (int i = 0; i < 4; ++i) {
#pragma unroll
        for (int j = 0; j < 4; ++j) {
#pragma unroll
            for (int r = 0; r < 4; ++r) {
                int row = m0 + wm + i * 16 + quad * 4 + r;
                int col = n0 + wn + j * 16 + r16;
                float v = acc[i][j][r] + bias[col];
                if (z < 2) {
                    dst[(long)row * 1024 + col] = (_Float16)v;
                } else {
                    int bb = row >> 10, s = row & 1023;
                    int hh = col >> 6, d = col & 63;
                    VtH[((((long)bb * 16 + hh) * 64 + d) << 10) | s] = (_Float16)v;
                }
            }
        }
    }
}

// ---------------------------------------------------------------------------
// Hedgehog feature map: per (b,h): Y = Xh @ Wf^T + bf (K=64), out = fp16
// [exp(Y) | exp(-Y)] into (B,H,S,128). Small VALU GEMM, 64x64 tile per block.
// ---------------------------------------------------------------------------
__global__ __launch_bounds__(256) void feat_map(
    const _Float16* __restrict__ Xh, const _Float16* __restrict__ Wf,
    const float* __restrict__ bf, _Float16* __restrict__ outH)
{
    const int z = blockIdx.y, b = z >> 4, h = z & 15;
    const int m0 = blockIdx.x * 64;
    __shared__ float Xs[64][65];
    __shared__ float Ws[64][65];
    const _Float16* Xb = Xh + (long)b * SD + h * 64;
    for (int i = threadIdx.x; i < 4096; i += 256) {
        int r = i >> 6, c = i & 63;
        Xs[r][c] = (float)Xb[(long)(m0 + r) * 1024 + c];
        Ws[r][c] = (float)Wf[i];
    }
    __syncthreads();
    const int tm = (threadIdx.x >> 4) * 4, tn = (threadIdx.x & 15) * 4;
    float acc[4][4] = {{0.f}};
    for (int k = 0; k < 64; ++k) {
        float xv[4], wv[4];
#pragma unroll
        for (int i = 0; i < 4; ++i) xv[i] = Xs[tm + i][k];
#pragma unroll
        for (int j = 0; j < 4; ++j) wv[j] = Ws[tn + j][k];
#pragma unroll
        for (int i = 0; i < 4; ++i)
#pragma unroll
            for (int j = 0; j < 4; ++j) acc[i][j] = fmaf(xv[i], wv[j], acc[i][j]);
    }
#pragma unroll
    for (int i = 0; i < 4; ++i) {
        long base = ((long)z * S_ + m0 + tm + i) * 128;
#pragma unroll
        for (int j = 0; j < 4; ++j) {
            float y = acc[i][j] + bf[tn + j];
            outH[base + tn + j]      = (_Float16)expf(y);
            outH[base + 64 + tn + j] = (_Float16)expf(-y);
        }
    }
}

// ---------------------------------------------------------------------------
// In-place softmax over rows of length 1024. One block (256 thr) per row.
// ---------------------------------------------------------------------------
__global__ __launch_bounds__(256) void softmax_rows(float* __restrict__ data)
{
    const long row = blockIdx.x;
    float* p = data + row * (long)S_;
    const int t = threadIdx.x;
    float x[4];
#pragma unroll
    for (int i = 0; i < 4; ++i) x[i] = p[t + i * 256];

    float m = fmaxf(fmaxf(x[0], x[1]), fmaxf(x[2], x[3]));
#pragma unroll
    for (int o = 32; o > 0; o >>= 1) m = fmaxf(m, __shfl_down(m, o, 64));
    __shared__ float sm[4];
    if ((t & 63) == 0) sm[t >> 6] = m;
    __syncthreads();
    m = fmaxf(fmaxf(sm[0], sm[1]), fmaxf(sm[2], sm[3]));

    float s = 0.f;
#pragma unroll
    for (int i = 0; i < 4; ++i) { x[i] = expf(x[i] - m); s += x[i]; }
#pragma unroll
    for (int o = 32; o > 0; o >>= 1) s += __shfl_down(s, o, 64);
    __shared__ float ss[4];
    if ((t & 63) == 0) ss[t >> 6] = s;
    __syncthreads();
    s = ss[0] + ss[1] + ss[2] + ss[3];

    float inv = 1.f / s;
#pragma unroll
    for (int i = 0; i < 4; ++i) p[t + i * 256] = x[i] * inv;
}

// ---------------------------------------------------------------------------
// In-place sum-normalize over rows of length 1024 (pred_attns).
// ---------------------------------------------------------------------------
__global__ __launch_bounds__(256) void norm_rows(float* __restrict__ data)
{
    const long row = blockIdx.x;
    float* p = data + row * (long)S_;
    const int t = threadIdx.x;
    float x[4];
#pragma unroll
    for (int i = 0; i < 4; ++i) x[i] = p[t + i * 256];

    float s = x[0] + x[1] + x[2] + x[3];
#pragma unroll
    for (int o = 32; o > 0; o >>= 1) s += __shfl_down(s, o, 64);
    __shared__ float ss[4];
    if ((t & 63) == 0) ss[t >> 6] = s;
    __syncthreads();
    s = ss[0] + ss[1] + ss[2] + ss[3];

    float inv = 1.f / s;
#pragma unroll
    for (int i = 0; i < 4; ++i) p[t + i * 256] = x[i] * inv;
}

// ---------------------------------------------------------------------------
extern "C" void kernel_launch(void* const* d_in, const int* in_sizes, int n_in,
                              void* d_out, int out_size, void* d_ws, size_t ws_size,
                              hipStream_t stream)
{
    (void)in_sizes; (void)n_in; (void)out_size; (void)ws_size;

    const float* hs  = (const float*)d_in[0];
    const float* Wq  = (const float*)d_in[1];
    const float* bq  = (const float*)d_in[2];
    const float* Wk  = (const float*)d_in[3];
    const float* bk  = (const float*)d_in[4];
    const float* Wv  = (const float*)d_in[5];
    const float* bv  = (const float*)d_in[6];
    const float* Wo  = (const float*)d_in[7];
    const float* bo  = (const float*)d_in[8];
    const float* Wfq = (const float*)d_in[9];
    const float* bfq = (const float*)d_in[10];
    const float* Wfk = (const float*)d_in[11];
    const float* bfk = (const float*)d_in[12];

    float* out0  = (float*)d_out;                       // (B,S,DM)
    float* pred  = out0 + (long)B_ * S_ * DM_;          // (B,H,S,S)
    float* trueA = pred + (long)B_ * NH_ * S_ * S_;     // (B,H,S,S)

    // workspace carve (halves), ~45 MB total
    _Float16* hsH  = (_Float16*)d_ws;                   // 2M
    _Float16* WqH  = hsH + 2 * 1024 * 1024;             // 1M each
    _Float16* WkH  = WqH + 1024 * 1024;
    _Float16* WvH  = WkH + 1024 * 1024;
    _Float16* WoH  = WvH + 1024 * 1024;
    _Float16* WfqH = WoH + 1024 * 1024;                 // 4096 each
    _Float16* WfkH = WfqH + 4096;
    _Float16* QH   = WfkH + 4096;                       // 2M each
    _Float16* KH   = QH + 2 * 1024 * 1024;
    _Float16* VtH  = KH + 2 * 1024 * 1024;              // (B,H,D,S)
    _Float16* ctxH = VtH + 2 * 1024 * 1024;             // (B,S,DM)
    _Float16* fqH  = ctxH + 2 * 1024 * 1024;            // (B,H,S,128)
    _Float16* fkH  = fqH + (long)B_ * NH_ * S_ * 128;

    const dim3 blk(256);

    // 0) fp32 -> fp16 input conversions
    cvt_f2h<<<2048, blk, 0, stream>>>(hs, hsH, 512 * 1024);
    cvt_f2h<<<1024, blk, 0, stream>>>(Wq, WqH, 256 * 1024);
    cvt_f2h<<<1024, blk, 0, stream>>>(Wk, WkH, 256 * 1024);
    cvt_f2h<<<1024, blk, 0, stream>>>(Wv, WvH, 256 * 1024);
    cvt_f2h<<<1024, blk, 0, stream>>>(Wo, WoH, 256 * 1024);
    cvt_f2h<<<4, blk, 0, stream>>>(Wfq, WfqH, 1024);
    cvt_f2h<<<4, blk, 0, stream>>>(Wfk, WfkH, 1024);

    // 1) fused QKV projection (V transposed per head)
    qkv_proj<<<dim3(8, 16, 3), blk, 0, stream>>>(
        hsH, WqH, WkH, WvH, bq, bk, bv, QH, KH, VtH);

    // 2) scores -> trueA (fp32): per (b,h): Qh @ Kh^T / 8, K=64
    mm_nt<128, 128, 64, 64, 0><<<dim3(8, 8, 32), blk, 0, stream>>>(
        QH, KH, nullptr, trueA, nullptr, 64, 1024, 1024, 1024,
        SD, 64, SD, 64, 16 * SS, SS, 0.125f, 0);

    // 3) softmax in place
    softmax_rows<<<B_ * NH_ * S_, blk, 0, stream>>>(trueA);

    // 4) ctx = P @ V -> ctxH fp16 in (B,S,DM) layout. A = trueA fp32 (convert
    //    in staging), W = VtH (N=64, K=1024, k-contiguous)
    mm_nt<128, 64, 64, 32, 1><<<dim3(1, 8, 32), blk, 0, stream>>>(
        trueA, VtH, nullptr, nullptr, ctxH, 1024, 1024, 1024, 1024,
        16 * SS, SS, (long)16 * 64 * 1024, (long)64 * 1024, SD, 64, 1.f, 1);

    // 5) outputs = ctx @ Wo^T + bo (fp32 out)
    mm_nt<128, 128, 64, 64, 0><<<dim3(8, 16, 1), blk, 0, stream>>>(
        ctxH, WoH, bo, out0, nullptr, 1024, 1024, 1024, 1024,
        0, 0, 0, 0, 0, 0, 1.f, 0);

    // 6) feature maps -> fqH, fkH (fp16, (B,H,S,128))
    feat_map<<<dim3(16, 32), blk, 0, stream>>>(QH, WfqH, bfq, fqH);
    feat_map<<<dim3(16, 32), blk, 0, stream>>>(KH, WfkH, bfk, fkH);

    // 7) qk -> pred (fp32): per (b,h): fq @ fk^T, K=128
    mm_nt<128, 128, 64, 64, 0><<<dim3(8, 8, 32), blk, 0, stream>>>(
        fqH, fkH, nullptr, pred, nullptr, 128, 128, 128, 1024,
        (long)16 * S_ * 128, (long)S_ * 128,
        (long)16 * S_ * 128, (long)S_ * 128,
        16 * SS, SS, 1.f, 0);

    // 8) sum-normalize rows in place
    norm_rows<<<B_ * NH_ * S_, blk, 0, stream>>>(pred);
}